// Round 1
// baseline (878.804 us; speedup 1.0000x reference)
//
#include <hip/hip_runtime.h>
#include <hip/hip_bf16.h>

#define N_NODESC 50000
#define N_EDGESC 800000
#define DD 128
#define HH 8
#define HDIM 16
#define N_NT 3
#define N_ET 5

// ---------------- workspace layout (bytes) ----------------
#define Q_OFF      ((size_t)0)           // f32 [N][128]  25.6 MB
#define K_OFF      ((size_t)25600000)    // f32 [N][128]  25.6 MB (dead after ktrans)
#define V_OFF      ((size_t)51200000)    // f32 [N][128]  25.6 MB (dead after edgeagg)
#define KT_OFF     ((size_t)76800000)    // bf16 [N][5][128] 64 MB (dead after edgeagg)
#define AGG_OFF    ((size_t)140800000)   // f32 [N][128]  25.6 MB
#define H1_OFF     ((size_t)166400000)   // f32 [N][128]  25.6 MB
#define ELIST_OFF  ((size_t)192000000)   // int [E]        3.2 MB
#define ROWS_OFF   ((size_t)195200000)   // int [N+1]      200,004 -> pad
#define DEG_OFF    ((size_t)195400064)   // int [N]        200,000
#define CUR_OFF    ((size_t)195600064)   // int [N]        200,000
#define T_OFF      K_OFF                 // f32 [N][512] 102.4 MB overlays K|V|Kt (all dead)

__device__ __forceinline__ float dot16(const float* xr, const float* w) {
    float a = 0.f;
#pragma unroll
    for (int d = 0; d < 16; d++) a = fmaf(xr[d], w[d], a);
    return a;
}

// ---------------- QKV: per-(node_type,head) 16x16 projections ----------------
// grid (782, 3): blockIdx.y selects Q/K/V matrix; 128 thr = (h,j); 64 nodes/block
__global__ __launch_bounds__(128) void qkv_kernel(
    const float* __restrict__ x, const int* __restrict__ ntype,
    const float* __restrict__ Wq, const float* __restrict__ Wk, const float* __restrict__ Wv,
    float* __restrict__ Q, float* __restrict__ K, float* __restrict__ V)
{
    const int tid = threadIdx.x;
    const int h = tid >> 4, j = tid & 15;
    const float* W = (blockIdx.y == 0) ? Wq : (blockIdx.y == 1) ? Wk : Wv;
    float* O = (blockIdx.y == 0) ? Q : (blockIdx.y == 1) ? K : V;

    float w[N_NT][HDIM];
#pragma unroll
    for (int t = 0; t < N_NT; t++)
#pragma unroll
        for (int d = 0; d < HDIM; d++)
            w[t][d] = W[((t * HH + h) * HDIM + d) * HDIM + j];

    __shared__ float xs[DD];
    const int base = blockIdx.x * 64;
    for (int nn = 0; nn < 64; nn++) {
        const int n = base + nn;
        __syncthreads();
        if (n < N_NODESC) xs[tid] = x[(size_t)n * DD + tid];
        __syncthreads();
        if (n >= N_NODESC) continue;
        const int t = ntype[n];
        float xr[HDIM];
#pragma unroll
        for (int d = 0; d < HDIM; d++) xr[d] = xs[h * HDIM + d];
        float acc;
        if (t == 0)      acc = dot16(xr, w[0]);
        else if (t == 1) acc = dot16(xr, w[1]);
        else             acc = dot16(xr, w[2]);
        O[(size_t)n * DD + tid] = acc;
    }
}

// ---------------- Kt[n][et][h][f] = sum_d K[n,h,d] * W_edge[et,h,d,f]  (bf16 out) ----
__global__ __launch_bounds__(128) void ktrans_kernel(
    const float* __restrict__ K, const float* __restrict__ We,
    __hip_bfloat16* __restrict__ Kt)
{
    const int tid = threadIdx.x;
    const int h = tid >> 4, j = tid & 15;
    float w[N_ET][HDIM];
#pragma unroll
    for (int et = 0; et < N_ET; et++)
#pragma unroll
        for (int d = 0; d < HDIM; d++)
            w[et][d] = We[((et * HH + h) * HDIM + d) * HDIM + j];

    __shared__ float ks[DD];
    const int base = blockIdx.x * 64;
    for (int nn = 0; nn < 64; nn++) {
        const int n = base + nn;
        __syncthreads();
        if (n < N_NODESC) ks[tid] = K[(size_t)n * DD + tid];
        __syncthreads();
        if (n >= N_NODESC) continue;
        float kr[HDIM];
#pragma unroll
        for (int d = 0; d < HDIM; d++) kr[d] = ks[h * HDIM + d];
#pragma unroll
        for (int et = 0; et < N_ET; et++) {
            float acc = dot16(kr, w[et]);
            Kt[((size_t)n * N_ET + et) * DD + tid] = __float2bfloat16(acc);
        }
    }
}

// ---------------- CSR build ----------------
__global__ void deg_kernel(const int* __restrict__ dst, int* __restrict__ deg) {
    const int e = blockIdx.x * 256 + threadIdx.x;
    if (e < N_EDGESC) atomicAdd(&deg[dst[e]], 1);
}

__global__ __launch_bounds__(1024) void scan_kernel(
    const int* __restrict__ deg, int* __restrict__ rowstart)
{
    __shared__ int part[1024];
    const int tid = threadIdx.x;
    const int per = 49;  // 1024*49 = 50176 >= 50000
    const int base = tid * per;
    int s = 0;
    for (int i = 0; i < per; i++) { int idx = base + i; if (idx < N_NODESC) s += deg[idx]; }
    part[tid] = s;
    __syncthreads();
    for (int off = 1; off < 1024; off <<= 1) {
        int v = (tid >= off) ? part[tid - off] : 0;
        __syncthreads();
        part[tid] += v;
        __syncthreads();
    }
    int run = (tid == 0) ? 0 : part[tid - 1];
    for (int i = 0; i < per; i++) {
        int idx = base + i;
        if (idx < N_NODESC) { rowstart[idx] = run; run += deg[idx]; }
    }
    if (tid == 1023) rowstart[N_NODESC] = part[1023];
}

__global__ void fill_kernel(const int* __restrict__ dst, const int* __restrict__ rowstart,
                            int* __restrict__ cursor, int* __restrict__ elist) {
    const int e = blockIdx.x * 256 + threadIdx.x;
    if (e < N_EDGESC) {
        const int d = dst[e];
        const int p = atomicAdd(&cursor[d], 1);
        elist[rowstart[d] + p] = e;
    }
}

// ---------------- fused edge pass: scores + softmax + V-aggregation ----------------
// one block (128 thr) per dst node; thread = output feature f, h = f>>4
// softmax shift skipped: scores are O(1e-3) (W scale 0.02) so exp() is exactly safe;
// w = ex/(den+1e-10) == (sum ex*V)/(den+1e-10), shift-invariance error ~6e-12 rel.
__global__ __launch_bounds__(128) void edgeagg_kernel(
    const int* __restrict__ src, const int* __restrict__ etype,
    const int* __restrict__ rowstart, const int* __restrict__ elist,
    const float* __restrict__ Q, const float* __restrict__ V,
    const __hip_bfloat16* __restrict__ Kt, const float* __restrict__ mu,
    float* __restrict__ agg)
{
    const int n = blockIdx.x;
    const int f = threadIdx.x;
    const int h = f >> 4;
    __shared__ float mus[HH * N_ET];
    if (f < HH * N_ET) mus[f] = mu[f];
    __syncthreads();

    const float qv = Q[(size_t)n * DD + f];
    const int s0 = rowstart[n], s1 = rowstart[n + 1];
    float acc = 0.f, den = 0.f;
    for (int i = s0; i < s1; i++) {
        const int e  = elist[i];
        const int s  = src[e];
        const int et = etype[e];
        float p = qv * __bfloat162float(Kt[((size_t)s * N_ET + et) * DD + f]);
        p += __shfl_xor(p, 1); p += __shfl_xor(p, 2);
        p += __shfl_xor(p, 4); p += __shfl_xor(p, 8);           // dot over 16 lanes
        const float ex = __expf(p * 0.25f * mus[h * N_ET + et]); // /sqrt(16) * mu
        den += ex;
        acc += ex * V[(size_t)s * DD + f];
    }
    agg[(size_t)n * DD + f] = acc / (den + 1e-10f);
}

// ---------------- fp32 GEMM tile: 128m x 128n, Kc=32, 256 thr, 8x8 per thread ----
#define KC 32
#define AS_LD 36   // 32+4 pad, keeps 16B alignment
#define BS_LD 132  // 128+4 pad

__device__ __forceinline__ void gemm_tile(
    const float* __restrict__ A, int lda,
    const float* __restrict__ B, int ldb, int nBase,
    int Ktot, int mBase, float* As, float* Bs, float (&acc)[8][8])
{
    const int tid = threadIdx.x;
#pragma unroll
    for (int i = 0; i < 8; i++)
#pragma unroll
        for (int j = 0; j < 8; j++) acc[i][j] = 0.f;

    for (int kc = 0; kc < Ktot; kc += KC) {
        {   // A tile 128 x 32 (row m, col k)
            const int am = tid >> 3;
            const int ak = (tid & 7) * 4;
#pragma unroll
            for (int r = 0; r < 4; r++) {
                const int m = am + r * 32;
                const int gm = mBase + m;
                float4 v = make_float4(0.f, 0.f, 0.f, 0.f);
                if (gm < N_NODESC) v = *(const float4*)(A + (size_t)gm * lda + kc + ak);
                *(float4*)(As + m * AS_LD + ak) = v;
            }
        }
        {   // B tile 32 x 128
            const int bk = tid >> 5;
            const int bc = (tid & 31) * 4;
#pragma unroll
            for (int r = 0; r < 4; r++) {
                const int k = bk + r * 8;
                float4 v = *(const float4*)(B + (size_t)(kc + k) * ldb + nBase + bc);
                *(float4*)(Bs + k * BS_LD + bc) = v;
            }
        }
        __syncthreads();
        const int m0 = (tid >> 4) * 8, f0 = (tid & 15) * 8;
#pragma unroll 8
        for (int k = 0; k < KC; k++) {
            float a[8], b[8];
#pragma unroll
            for (int i = 0; i < 8; i++) a[i] = As[(m0 + i) * AS_LD + k];
            *(float4*)(b)     = *(const float4*)(Bs + k * BS_LD + f0);
            *(float4*)(b + 4) = *(const float4*)(Bs + k * BS_LD + f0 + 4);
#pragma unroll
            for (int i = 0; i < 8; i++)
#pragma unroll
                for (int j = 0; j < 8; j++) acc[i][j] = fmaf(a[i], b[j], acc[i][j]);
        }
        __syncthreads();
    }
}

// epilogue: y = acc + resid + bias; LayerNorm over 128 feats; out = y_hat*g+b
__device__ __forceinline__ void ln_store(
    float (&acc)[8][8], const float* __restrict__ resid, const float* __restrict__ bias,
    const float* __restrict__ g, const float* __restrict__ b,
    float* __restrict__ out, int mBase)
{
    const int tid = threadIdx.x;
    const int m0 = (tid >> 4) * 8, f0 = (tid & 15) * 8;
#pragma unroll
    for (int i = 0; i < 8; i++) {
        const int gm = mBase + m0 + i;
        if (gm >= N_NODESC) continue;   // uniform across the 16-lane shuffle group
        float y[8]; float s = 0.f, ss = 0.f;
#pragma unroll
        for (int j = 0; j < 8; j++) {
            float v = acc[i][j] + resid[(size_t)gm * DD + f0 + j] + bias[f0 + j];
            y[j] = v; s += v; ss += v * v;
        }
        s  += __shfl_xor(s, 1);  s  += __shfl_xor(s, 2);  s  += __shfl_xor(s, 4);  s  += __shfl_xor(s, 8);
        ss += __shfl_xor(ss, 1); ss += __shfl_xor(ss, 2); ss += __shfl_xor(ss, 4); ss += __shfl_xor(ss, 8);
        const float mean = s * (1.f / 128.f);
        const float var  = ss * (1.f / 128.f) - mean * mean;
        const float rstd = rsqrtf(var + 1e-5f);
#pragma unroll
        for (int j = 0; j < 8; j++)
            out[(size_t)gm * DD + f0 + j] = (y[j] - mean) * rstd * g[f0 + j] + b[f0 + j];
    }
}

__global__ __launch_bounds__(256) void attn_out_kernel(
    const float* __restrict__ agg, const float* __restrict__ Wout,
    const float* __restrict__ bout, const float* __restrict__ x,
    const float* __restrict__ g, const float* __restrict__ b, float* __restrict__ h1)
{
    __shared__ float As[128 * AS_LD];
    __shared__ float Bs[KC * BS_LD];
    float acc[8][8];
    gemm_tile(agg, 128, Wout, 128, 0, 128, blockIdx.x * 128, As, Bs, acc);
    ln_store(acc, x, bout, g, b, h1, blockIdx.x * 128);
}

__global__ __launch_bounds__(256) void ffn1_kernel(
    const float* __restrict__ h1, const float* __restrict__ W1,
    const float* __restrict__ b1, float* __restrict__ T)
{
    __shared__ float As[128 * AS_LD];
    __shared__ float Bs[KC * BS_LD];
    float acc[8][8];
    const int nb = blockIdx.y * 128;
    gemm_tile(h1, 128, W1, 512, nb, 128, blockIdx.x * 128, As, Bs, acc);
    const int tid = threadIdx.x;
    const int m0 = (tid >> 4) * 8, f0 = (tid & 15) * 8;
#pragma unroll
    for (int i = 0; i < 8; i++) {
        const int gm = blockIdx.x * 128 + m0 + i;
        if (gm >= N_NODESC) continue;
#pragma unroll
        for (int j = 0; j < 8; j++) {
            const float v = acc[i][j] + b1[nb + f0 + j];
            const float ge = 0.5f * v * (1.f + erff(v * 0.70710678118654752f)); // exact gelu
            T[(size_t)gm * 512 + nb + f0 + j] = ge;
        }
    }
}

__global__ __launch_bounds__(256) void ffn2_kernel(
    const float* __restrict__ T, const float* __restrict__ W2,
    const float* __restrict__ b2, const float* __restrict__ h1,
    const float* __restrict__ g, const float* __restrict__ b, float* __restrict__ out)
{
    __shared__ float As[128 * AS_LD];
    __shared__ float Bs[KC * BS_LD];
    float acc[8][8];
    gemm_tile(T, 512, W2, 128, 0, 512, blockIdx.x * 128, As, Bs, acc);
    ln_store(acc, h1, b2, g, b, out, blockIdx.x * 128);
}

extern "C" void kernel_launch(void* const* d_in, const int* in_sizes, int n_in,
                              void* d_out, int out_size, void* d_ws, size_t ws_size,
                              hipStream_t stream)
{
    const float* x     = (const float*)d_in[0];
    const int*   ei    = (const int*)d_in[1];
    const int*   etyp  = (const int*)d_in[2];
    const int*   ntype = (const int*)d_in[3];
    const float* Wq    = (const float*)d_in[4];
    const float* Wk    = (const float*)d_in[5];
    const float* Wv    = (const float*)d_in[6];
    const float* We    = (const float*)d_in[7];
    const float* mu    = (const float*)d_in[8];
    const float* Wout  = (const float*)d_in[9];
    const float* bout  = (const float*)d_in[10];
    const float* g1    = (const float*)d_in[11];
    const float* b1ln  = (const float*)d_in[12];
    const float* W1    = (const float*)d_in[13];
    const float* b1    = (const float*)d_in[14];
    const float* W2    = (const float*)d_in[15];
    const float* b2    = (const float*)d_in[16];
    const float* g2    = (const float*)d_in[17];
    const float* b2ln  = (const float*)d_in[18];
    float* out = (float*)d_out;

    char* ws = (char*)d_ws;
    float*          Q     = (float*)(ws + Q_OFF);
    float*          K     = (float*)(ws + K_OFF);
    float*          V     = (float*)(ws + V_OFF);
    __hip_bfloat16* Kt    = (__hip_bfloat16*)(ws + KT_OFF);
    float*          agg   = (float*)(ws + AGG_OFF);
    float*          h1    = (float*)(ws + H1_OFF);
    int*            elist = (int*)(ws + ELIST_OFF);
    int*            rows  = (int*)(ws + ROWS_OFF);
    int*            deg   = (int*)(ws + DEG_OFF);
    int*            cur   = (int*)(ws + CUR_OFF);
    float*          T     = (float*)(ws + T_OFF);

    const int* srcA = ei;              // edge_index[0]
    const int* dstA = ei + N_EDGESC;   // edge_index[1]

    // zero deg + cursor (contiguous)
    hipMemsetAsync(ws + DEG_OFF, 0, (CUR_OFF - DEG_OFF) + 200000, stream);

    qkv_kernel<<<dim3(782, 3), 128, 0, stream>>>(x, ntype, Wq, Wk, Wv, Q, K, V);
    ktrans_kernel<<<782, 128, 0, stream>>>(K, We, Kt);
    deg_kernel<<<3125, 256, 0, stream>>>(dstA, deg);
    scan_kernel<<<1, 1024, 0, stream>>>(deg, rows);
    fill_kernel<<<3125, 256, 0, stream>>>(dstA, rows, cur, elist);
    edgeagg_kernel<<<N_NODESC, 128, 0, stream>>>(srcA, etyp, rows, elist, Q, V, Kt, mu, agg);
    attn_out_kernel<<<391, 256, 0, stream>>>(agg, Wout, bout, x, g1, b1ln, h1);
    ffn1_kernel<<<dim3(391, 4), 256, 0, stream>>>(h1, W1, b1, T);
    ffn2_kernel<<<391, 256, 0, stream>>>(T, W2, b2, h1, g2, b2ln, out);
}

// Round 2
// 652.766 us; speedup vs baseline: 1.3463x; 1.3463x over previous
//
#include <hip/hip_runtime.h>
#include <hip/hip_bf16.h>

#define N_NODESC 50000
#define N_EDGESC 800000
#define DD 128
#define HH 8
#define HDIM 16
#define N_NT 3
#define N_ET 5

// ---------------- workspace layout (bytes), total <= 195.8 MB ----------------
#define KV_OFF     ((size_t)0)           // bf16 [N][256] K|V packed, 25.6 MB (dead after edgeagg)
#define QT_OFF     ((size_t)25600000)    // bf16 [N][5][128] 64 MB (dead after edgeagg)
#define AGG_OFF    ((size_t)89600000)    // bf16 [N][128] 12.8 MB (dead after attn gemm)
#define MM_OFF     ((size_t)102400000)   // f32 [N][128] 25.6 MB (gemm out, reused)
#define H1F_OFF    ((size_t)128000000)   // f32 [N][128] 25.6 MB
#define H1B_OFF    ((size_t)153600000)   // bf16 [N][128] 12.8 MB
#define WOUTT_OFF  ((size_t)166400000)   // bf16 [128][128] 32 KB
#define W1T_OFF    ((size_t)166432768)   // bf16 [512][128] 128 KB
#define W2T_OFF    ((size_t)166563840)   // bf16 [128][512] 128 KB
#define WC_OFF     ((size_t)166700032)   // f32 [5][3][8][16][16] 120 KB (dead after qt)
#define T_OFF      ((size_t)0)           // bf16 [N][512] 51.2 MB overlays KV+Qt (dead)
#define ELIST_OFF  ((size_t)192000000)   // int [E] 3.2 MB
#define ROWS_OFF   ((size_t)195200000)   // int [N+1]
#define DEG_OFF    ((size_t)195400064)   // int [N]
#define CUR_OFF    ((size_t)195600064)   // int [N]

using short8 = __attribute__((ext_vector_type(8))) short;
using f32x4  = __attribute__((ext_vector_type(4))) float;

__device__ __forceinline__ ushort f2b(float f) {
    __hip_bfloat16 h = __float2bfloat16(f);
    return *(ushort*)&h;
}
__device__ __forceinline__ float b2f(ushort u) {
    __hip_bfloat16 h = *(__hip_bfloat16*)&u;
    return __bfloat162float(h);
}
__device__ __forceinline__ float dot16(const float* xr, const float* w) {
    float a = 0.f;
#pragma unroll
    for (int d = 0; d < 16; d++) a = fmaf(xr[d], w[d], a);
    return a;
}

// ---- combined Q-side weights: Wc[et][t][h][c][d] = 0.25*mu[h,et]*sum_f WQ[t,h,c,f]*We[et,h,d,f]
__global__ __launch_bounds__(256) void wc_kernel(
    const float* __restrict__ WQ, const float* __restrict__ We,
    const float* __restrict__ mu, float* __restrict__ Wc)
{
    const int et = blockIdx.x, t = blockIdx.y, h = blockIdx.z;
    const int c = threadIdx.x >> 4, dd = threadIdx.x & 15;
    const float* wq = WQ + (((t * HH + h) * HDIM + c) * HDIM);
    const float* we = We + (((et * HH + h) * HDIM + dd) * HDIM);
    float s = 0.f;
#pragma unroll
    for (int f = 0; f < 16; f++) s = fmaf(wq[f], we[f], s);
    Wc[((((et * N_NT + t) * HH + h) * HDIM + c) * HDIM) + dd] = 0.25f * mu[h * N_ET + et] * s;
}

// ---- K,V projections -> packed bf16 KV[n][256]  (grid (782,2): y=0 K, y=1 V)
__global__ __launch_bounds__(128) void kv_kernel(
    const float* __restrict__ x, const int* __restrict__ ntype,
    const float* __restrict__ Wk, const float* __restrict__ Wv,
    ushort* __restrict__ KV)
{
    const int tid = threadIdx.x;
    const int h = tid >> 4;
    const int j = tid & 15;
    const float* W = (blockIdx.y == 0) ? Wk : Wv;
    const int ofs = (blockIdx.y == 0) ? 0 : 128;

    float w[N_NT][HDIM];
#pragma unroll
    for (int t = 0; t < N_NT; t++)
#pragma unroll
        for (int d = 0; d < HDIM; d++)
            w[t][d] = W[((t * HH + h) * HDIM + d) * HDIM + j];

    __shared__ float xs[DD];
    const int base = blockIdx.x * 64;
    for (int nn = 0; nn < 64; nn++) {
        const int n = base + nn;
        __syncthreads();
        if (n < N_NODESC) xs[tid] = x[(size_t)n * DD + tid];
        __syncthreads();
        if (n >= N_NODESC) continue;
        const int t = ntype[n];
        float xr[HDIM];
#pragma unroll
        for (int d = 0; d < HDIM; d++) xr[d] = xs[h * HDIM + d];
        float acc;
        if (t == 0)      acc = dot16(xr, w[0]);
        else if (t == 1) acc = dot16(xr, w[1]);
        else             acc = dot16(xr, w[2]);
        KV[(size_t)n * 256 + ofs + tid] = f2b(acc);
    }
}

// ---- Qt[n][et][h*16+d] = sum_c x[n,h*16+c] * Wc[et,ntype,h,c,d]   (grid (782,5))
__global__ __launch_bounds__(128) void qt_kernel(
    const float* __restrict__ x, const int* __restrict__ ntype,
    const float* __restrict__ Wc, ushort* __restrict__ Qt)
{
    const int tid = threadIdx.x;
    const int h = tid >> 4, dd = tid & 15;
    const int et = blockIdx.y;
    float w[N_NT][HDIM];
#pragma unroll
    for (int t = 0; t < N_NT; t++)
#pragma unroll
        for (int c = 0; c < HDIM; c++)
            w[t][c] = Wc[((((et * N_NT + t) * HH + h) * HDIM + c) * HDIM) + dd];

    __shared__ float xs[DD];
    const int base = blockIdx.x * 64;
    for (int nn = 0; nn < 64; nn++) {
        const int n = base + nn;
        __syncthreads();
        if (n < N_NODESC) xs[tid] = x[(size_t)n * DD + tid];
        __syncthreads();
        if (n >= N_NODESC) continue;
        const int t = ntype[n];
        float xr[HDIM];
#pragma unroll
        for (int c = 0; c < HDIM; c++) xr[c] = xs[h * HDIM + c];
        float acc;
        if (t == 0)      acc = dot16(xr, w[0]);
        else if (t == 1) acc = dot16(xr, w[1]);
        else             acc = dot16(xr, w[2]);
        Qt[((size_t)n * N_ET + et) * DD + tid] = f2b(acc);
    }
}

// ---------------- CSR build ----------------
__global__ void deg_kernel(const int* __restrict__ dst, int* __restrict__ deg) {
    const int e = blockIdx.x * 256 + threadIdx.x;
    if (e < N_EDGESC) atomicAdd(&deg[dst[e]], 1);
}

__global__ __launch_bounds__(1024) void scan_kernel(
    const int* __restrict__ deg, int* __restrict__ rowstart)
{
    __shared__ int part[1024];
    const int tid = threadIdx.x;
    const int per = 49;
    const int base = tid * per;
    int s = 0;
    for (int i = 0; i < per; i++) { int idx = base + i; if (idx < N_NODESC) s += deg[idx]; }
    part[tid] = s;
    __syncthreads();
    for (int off = 1; off < 1024; off <<= 1) {
        int v = (tid >= off) ? part[tid - off] : 0;
        __syncthreads();
        part[tid] += v;
        __syncthreads();
    }
    int run = (tid == 0) ? 0 : part[tid - 1];
    for (int i = 0; i < per; i++) {
        int idx = base + i;
        if (idx < N_NODESC) { rowstart[idx] = run; run += deg[idx]; }
    }
    if (tid == 1023) rowstart[N_NODESC] = part[1023];
}

__global__ void fill_kernel(const int* __restrict__ dst, const int* __restrict__ rowstart,
                            int* __restrict__ cursor, int* __restrict__ elist) {
    const int e = blockIdx.x * 256 + threadIdx.x;
    if (e < N_EDGESC) {
        const int d = dst[e];
        const int p = atomicAdd(&cursor[d], 1);
        elist[rowstart[d] + p] = e;
    }
}

// ---------------- fused edge pass ----------------
// block = dst node; thread f = feature; gathers only bf16 KV rows (25.6MB working set)
__global__ __launch_bounds__(128) void edgeagg_kernel(
    const int* __restrict__ src, const int* __restrict__ etype,
    const int* __restrict__ rowstart, const int* __restrict__ elist,
    const ushort* __restrict__ Qt, const ushort* __restrict__ KV,
    ushort* __restrict__ agg)
{
    const int n = blockIdx.x;
    const int f = threadIdx.x;
    // Qt rows for this node, scale+mu prefolded
    float q0 = b2f(Qt[((size_t)n * N_ET + 0) * DD + f]);
    float q1 = b2f(Qt[((size_t)n * N_ET + 1) * DD + f]);
    float q2 = b2f(Qt[((size_t)n * N_ET + 2) * DD + f]);
    float q3 = b2f(Qt[((size_t)n * N_ET + 3) * DD + f]);
    float q4 = b2f(Qt[((size_t)n * N_ET + 4) * DD + f]);

    const int s0 = rowstart[n], s1 = rowstart[n + 1];
    float acc = 0.f, den = 0.f;
    int i = s0;
    for (; i + 1 < s1; i += 2) {
        const int e0 = elist[i], e1 = elist[i + 1];
        const int sA = src[e0], sB = src[e1];
        const int eA = etype[e0], eB = etype[e1];
        const float kA = b2f(KV[(size_t)sA * 256 + f]);
        const float kB = b2f(KV[(size_t)sB * 256 + f]);
        const float vA = b2f(KV[(size_t)sA * 256 + 128 + f]);
        const float vB = b2f(KV[(size_t)sB * 256 + 128 + f]);
        const float qA = (eA == 0) ? q0 : (eA == 1) ? q1 : (eA == 2) ? q2 : (eA == 3) ? q3 : q4;
        const float qB = (eB == 0) ? q0 : (eB == 1) ? q1 : (eB == 2) ? q2 : (eB == 3) ? q3 : q4;
        float pA = qA * kA, pB = qB * kB;
        pA += __shfl_xor(pA, 1); pB += __shfl_xor(pB, 1);
        pA += __shfl_xor(pA, 2); pB += __shfl_xor(pB, 2);
        pA += __shfl_xor(pA, 4); pB += __shfl_xor(pB, 4);
        pA += __shfl_xor(pA, 8); pB += __shfl_xor(pB, 8);
        const float exA = __expf(pA), exB = __expf(pB);
        den += exA + exB;
        acc = fmaf(exA, vA, acc);
        acc = fmaf(exB, vB, acc);
    }
    if (i < s1) {
        const int e0 = elist[i];
        const int sA = src[e0];
        const int eA = etype[e0];
        const float kA = b2f(KV[(size_t)sA * 256 + f]);
        const float vA = b2f(KV[(size_t)sA * 256 + 128 + f]);
        const float qA = (eA == 0) ? q0 : (eA == 1) ? q1 : (eA == 2) ? q2 : (eA == 3) ? q3 : q4;
        float pA = qA * kA;
        pA += __shfl_xor(pA, 1); pA += __shfl_xor(pA, 2);
        pA += __shfl_xor(pA, 4); pA += __shfl_xor(pA, 8);
        const float exA = __expf(pA);
        den += exA;
        acc = fmaf(exA, vA, acc);
    }
    agg[(size_t)n * DD + f] = f2b(acc / (den + 1e-10f));
}

// ---- weight transposes to bf16 [N][K] for MFMA B-operand ----
__global__ __launch_bounds__(256) void convert_wt(
    const float* __restrict__ Wout, const float* __restrict__ W1, const float* __restrict__ W2,
    ushort* __restrict__ Woutt, ushort* __restrict__ W1t, ushort* __restrict__ W2t)
{
    const int gid = blockIdx.x * 256 + threadIdx.x;
    if (gid < 16384) {                       // Woutt[n][k] = Wout[k][n], 128x128
        const int nn = gid >> 7, k = gid & 127;
        Woutt[gid] = f2b(Wout[k * 128 + nn]);
    } else if (gid < 16384 + 65536) {        // W1t[n][k] = W1[k][n], n<512,k<128
        const int i = gid - 16384;
        const int nn = i >> 7, k = i & 127;
        W1t[i] = f2b(W1[k * 512 + nn]);
    } else if (gid < 16384 + 131072) {       // W2t[n][k] = W2[k][n], n<128,k<512
        const int i = gid - 81920;
        const int nn = i >> 9, k = i & 511;
        W2t[i] = f2b(W2[k * 128 + nn]);
    }
}

// ---------------- MFMA bf16 GEMM: 128x128 tile, BK=32, 4 waves (2x2 of 64x64) ----
// A [M x KT] bf16 row-major, Bt [N x KT] bf16 row-major (pre-transposed B).
// GELU: out = bf16 gelu(acc + bias) ; else out = f32 acc.
#define LDP 40  // padded LDS row stride (shorts): conflict-free b128 fragment reads

template<int KT, bool GELU>
__global__ __launch_bounds__(256) void mfma_gemm(
    const ushort* __restrict__ A, const ushort* __restrict__ Bt,
    const float* __restrict__ bias, float* __restrict__ Cf,
    ushort* __restrict__ Cb, int ldOut)
{
    __shared__ ushort As[128 * LDP];
    __shared__ ushort Bs[128 * LDP];
    const int tid = threadIdx.x;
    const int lane = tid & 63, wave = tid >> 6;
    const int mw = (wave >> 1) * 64, nw = (wave & 1) * 64;
    const int mBase = blockIdx.x * 128, nBase = blockIdx.y * 128;
    const int l15 = lane & 15, q8 = (lane >> 4) * 8;

    f32x4 acc[4][4];
#pragma unroll
    for (int i = 0; i < 4; i++)
#pragma unroll
        for (int j = 0; j < 4; j++) acc[i][j] = (f32x4){0.f, 0.f, 0.f, 0.f};

    const int r0 = tid >> 2;            // 0..63
    const int c0 = (tid & 3) * 8;       // k-chunk within BK=32

    for (int kk = 0; kk < KT; kk += 32) {
        const ushort* pa = A  + (size_t)(mBase + r0) * KT + kk + c0;
        const ushort* pb = Bt + (size_t)(nBase + r0) * KT + kk + c0;
        short8 a0 = *(const short8*)pa;
        short8 a1 = *(const short8*)(pa + (size_t)64 * KT);
        short8 b0 = *(const short8*)pb;
        short8 b1 = *(const short8*)(pb + (size_t)64 * KT);
        *(short8*)&As[r0 * LDP + c0] = a0;
        *(short8*)&As[(r0 + 64) * LDP + c0] = a1;
        *(short8*)&Bs[r0 * LDP + c0] = b0;
        *(short8*)&Bs[(r0 + 64) * LDP + c0] = b1;
        __syncthreads();

        short8 af[4], bf[4];
#pragma unroll
        for (int i = 0; i < 4; i++)
            af[i] = *(const short8*)&As[(mw + i * 16 + l15) * LDP + q8];
#pragma unroll
        for (int j = 0; j < 4; j++)
            bf[j] = *(const short8*)&Bs[(nw + j * 16 + l15) * LDP + q8];
#pragma unroll
        for (int i = 0; i < 4; i++)
#pragma unroll
            for (int j = 0; j < 4; j++)
                acc[i][j] = __builtin_amdgcn_mfma_f32_16x16x32_bf16(af[i], bf[j], acc[i][j], 0, 0, 0);
        __syncthreads();
    }

    // epilogue: C/D layout col=lane&15, row=(lane>>4)*4+reg
    const int rq = (lane >> 4) * 4;
#pragma unroll
    for (int i = 0; i < 4; i++) {
#pragma unroll
        for (int r = 0; r < 4; r++) {
            const int gm = mBase + mw + i * 16 + rq + r;
            if (gm >= N_NODESC) continue;
#pragma unroll
            for (int j = 0; j < 4; j++) {
                const int gn = nBase + nw + j * 16 + l15;
                float v = acc[i][j][r];
                if (GELU) {
                    v += bias[gn];
                    v = 0.5f * v * (1.f + erff(v * 0.70710678118654752f));
                    Cb[(size_t)gm * ldOut + gn] = f2b(v);
                } else {
                    Cf[(size_t)gm * ldOut + gn] = v;
                }
            }
        }
    }
}

// ---- residual + bias + LayerNorm; optional bf16 copy. 4 rows/block (1 per wave) ----
__global__ __launch_bounds__(256) void ln_kernel(
    const float* __restrict__ y, const float* __restrict__ resid,
    const float* __restrict__ bias, const float* __restrict__ g,
    const float* __restrict__ b, float* __restrict__ outF,
    ushort* __restrict__ outB)
{
    const int wave = threadIdx.x >> 6, lane = threadIdx.x & 63;
    const int row = blockIdx.x * 4 + wave;
    if (row >= N_NODESC) return;
    const size_t base = (size_t)row * DD;
    float v0 = y[base + lane] + resid[base + lane] + bias[lane];
    float v1 = y[base + 64 + lane] + resid[base + 64 + lane] + bias[64 + lane];
    float s = v0 + v1, ss = v0 * v0 + v1 * v1;
#pragma unroll
    for (int off = 1; off < 64; off <<= 1) {
        s += __shfl_xor(s, off);
        ss += __shfl_xor(ss, off);
    }
    const float mean = s * (1.f / 128.f);
    const float var = ss * (1.f / 128.f) - mean * mean;
    const float rstd = rsqrtf(var + 1e-5f);
    const float o0 = (v0 - mean) * rstd * g[lane] + b[lane];
    const float o1 = (v1 - mean) * rstd * g[64 + lane] + b[64 + lane];
    outF[base + lane] = o0;
    outF[base + 64 + lane] = o1;
    if (outB) {
        outB[base + lane] = f2b(o0);
        outB[base + 64 + lane] = f2b(o1);
    }
}

extern "C" void kernel_launch(void* const* d_in, const int* in_sizes, int n_in,
                              void* d_out, int out_size, void* d_ws, size_t ws_size,
                              hipStream_t stream)
{
    const float* x     = (const float*)d_in[0];
    const int*   ei    = (const int*)d_in[1];
    const int*   etyp  = (const int*)d_in[2];
    const int*   ntype = (const int*)d_in[3];
    const float* Wq    = (const float*)d_in[4];
    const float* Wk    = (const float*)d_in[5];
    const float* Wv    = (const float*)d_in[6];
    const float* We    = (const float*)d_in[7];
    const float* mu    = (const float*)d_in[8];
    const float* Wout  = (const float*)d_in[9];
    const float* bout  = (const float*)d_in[10];
    const float* g1    = (const float*)d_in[11];
    const float* b1ln  = (const float*)d_in[12];
    const float* W1    = (const float*)d_in[13];
    const float* b1    = (const float*)d_in[14];
    const float* W2    = (const float*)d_in[15];
    const float* b2    = (const float*)d_in[16];
    const float* g2    = (const float*)d_in[17];
    const float* b2ln  = (const float*)d_in[18];
    float* out = (float*)d_out;

    char* ws = (char*)d_ws;
    ushort* KV    = (ushort*)(ws + KV_OFF);
    ushort* Qt    = (ushort*)(ws + QT_OFF);
    ushort* agg   = (ushort*)(ws + AGG_OFF);
    float*  mm    = (float*)(ws + MM_OFF);
    float*  h1f   = (float*)(ws + H1F_OFF);
    ushort* h1b   = (ushort*)(ws + H1B_OFF);
    ushort* Woutt = (ushort*)(ws + WOUTT_OFF);
    ushort* W1t   = (ushort*)(ws + W1T_OFF);
    ushort* W2t   = (ushort*)(ws + W2T_OFF);
    float*  Wc    = (float*)(ws + WC_OFF);
    ushort* T     = (ushort*)(ws + T_OFF);
    int*    elist = (int*)(ws + ELIST_OFF);
    int*    rows  = (int*)(ws + ROWS_OFF);
    int*    deg   = (int*)(ws + DEG_OFF);
    int*    cur   = (int*)(ws + CUR_OFF);

    const int* srcA = ei;
    const int* dstA = ei + N_EDGESC;

    hipMemsetAsync(ws + DEG_OFF, 0, 400000 + 64, stream);

    convert_wt<<<576, 256, 0, stream>>>(Wout, W1, W2, Woutt, W1t, W2t);
    wc_kernel<<<dim3(N_ET, N_NT, HH), 256, 0, stream>>>(Wq, We, mu, Wc);
    kv_kernel<<<dim3(782, 2), 128, 0, stream>>>(x, ntype, Wk, Wv, KV);
    qt_kernel<<<dim3(782, N_ET), 128, 0, stream>>>(x, ntype, Wc, Qt);
    deg_kernel<<<3125, 256, 0, stream>>>(dstA, deg);
    scan_kernel<<<1, 1024, 0, stream>>>(deg, rows);
    fill_kernel<<<3125, 256, 0, stream>>>(dstA, rows, cur, elist);
    edgeagg_kernel<<<N_NODESC, 128, 0, stream>>>(srcA, etyp, rows, elist, Qt, KV, agg);

    // attn out: mm = agg @ Wout
    mfma_gemm<128, false><<<391, 256, 0, stream>>>(agg, Woutt, nullptr, mm, nullptr, 128);
    // h1 = LN(x + mm + bout)
    ln_kernel<<<12500, 256, 0, stream>>>(mm, x, bout, g1, b1ln, h1f, h1b);
    // T = gelu(h1 @ W1 + b1)   (bf16)
    mfma_gemm<128, true><<<dim3(391, 4), 256, 0, stream>>>(h1b, W1t, b1, nullptr, T, 512);
    // mm = T @ W2
    mfma_gemm<512, false><<<391, 256, 0, stream>>>(T, W2t, nullptr, mm, nullptr, 128);
    // out = LN(h1 + mm + b2)
    ln_kernel<<<12500, 256, 0, stream>>>(mm, h1f, b2, g2, b2ln, out, nullptr);
}

// Round 3
// 597.686 us; speedup vs baseline: 1.4703x; 1.0922x over previous
//
#include <hip/hip_runtime.h>
#include <hip/hip_bf16.h>

#define N_NODESC 50000
#define N_EDGESC 800000
#define DD 128
#define HH 8
#define HDIM 16
#define N_NT 3
#define N_ET 5

// ---------------- workspace layout (bytes) ----------------
#define KV_OFF     ((size_t)0)           // fp8 [N][128][2] K|V interleaved, 12.8 MB (dead after edgeagg)
#define QT8_OFF    ((size_t)12800000)    // fp8 [N][5][128] 32 MB (dead after edgeagg)
#define T_OFF      ((size_t)0)           // bf16 [N][512] 51.2 MB overlays KV+Qt8 (both dead at ffn1)
#define AGG_OFF    ((size_t)51200000)    // bf16 [N][128] 12.8 MB
#define H1B_OFF    ((size_t)64000000)    // bf16 [N][128] 12.8 MB
#define WOUTT_OFF  ((size_t)76800000)    // bf16 [128][128] 32 KB
#define W1T_OFF    ((size_t)76832768)    // bf16 [512][128] 128 KB
#define W2T_OFF    ((size_t)76963840)    // bf16 [128][512] 128 KB
#define WC_OFF     ((size_t)77094912)    // f32 [5][3][8][16][16] 120 KB
#define EDATA_OFF  ((size_t)77217792)    // int [E] packed src|et<<16, 3.2 MB
#define ROWS_OFF   ((size_t)80417792)    // int [N+1]
#define DEG_OFF    ((size_t)80617856)    // int [N]
#define CUR_OFF    ((size_t)80817856)    // int [N]

using short8 = __attribute__((ext_vector_type(8))) short;
using f32x4  = __attribute__((ext_vector_type(4))) float;

__device__ __forceinline__ ushort f2b(float f) {
    __hip_bfloat16 h = __float2bfloat16(f);
    return *(ushort*)&h;
}
__device__ __forceinline__ float b2f(ushort u) {
    __hip_bfloat16 h = *(__hip_bfloat16*)&u;
    return __bfloat162float(h);
}
__device__ __forceinline__ float dot16(const float* xr, const float* w) {
    float a = 0.f;
#pragma unroll
    for (int d = 0; d < 16; d++) a = fmaf(xr[d], w[d], a);
    return a;
}

// ---- combined Q-side weights: Wc[et][t][h][c][d] = 64*mu[h,et]*sum_f WQ[t,h,c,f]*We[et,h,d,f]
// 64 = 256 (Qt fp8 scale) * 0.25 (1/sqrt(HD)); with K scaled x4, exp arg = p/1024.
__global__ __launch_bounds__(256) void wc_kernel(
    const float* __restrict__ WQ, const float* __restrict__ We,
    const float* __restrict__ mu, float* __restrict__ Wc)
{
    const int et = blockIdx.x, t = blockIdx.y, h = blockIdx.z;
    const int c = threadIdx.x >> 4, dd = threadIdx.x & 15;
    const float* wq = WQ + (((t * HH + h) * HDIM + c) * HDIM);
    const float* we = We + (((et * HH + h) * HDIM + dd) * HDIM);
    float s = 0.f;
#pragma unroll
    for (int f = 0; f < 16; f++) s = fmaf(wq[f], we[f], s);
    Wc[((((et * N_NT + t) * HH + h) * HDIM + c) * HDIM) + dd] = 64.f * mu[h * N_ET + et] * s;
}

// ---- K,V projections -> fp8 interleaved KV[n][f] = {K8,V8} (both scaled x4) ----
__global__ __launch_bounds__(128) void kv_kernel(
    const float* __restrict__ x, const int* __restrict__ ntype,
    const float* __restrict__ Wk, const float* __restrict__ Wv,
    ushort* __restrict__ KV)
{
    const int tid = threadIdx.x;
    const int h = tid >> 4, j = tid & 15;
    float wk[N_NT][HDIM], wv[N_NT][HDIM];
#pragma unroll
    for (int t = 0; t < N_NT; t++)
#pragma unroll
        for (int d = 0; d < HDIM; d++) {
            wk[t][d] = Wk[((t * HH + h) * HDIM + d) * HDIM + j];
            wv[t][d] = Wv[((t * HH + h) * HDIM + d) * HDIM + j];
        }

    __shared__ float xs[DD];
    const int base = blockIdx.x * 64;
    for (int nn = 0; nn < 64; nn++) {
        const int n = base + nn;
        __syncthreads();
        if (n < N_NODESC) xs[tid] = x[(size_t)n * DD + tid];
        __syncthreads();
        if (n >= N_NODESC) continue;
        const int t = ntype[n];
        float xr[HDIM];
#pragma unroll
        for (int d = 0; d < HDIM; d++) xr[d] = xs[h * HDIM + d];
        float k, v;
        if (t == 0)      { k = dot16(xr, wk[0]); v = dot16(xr, wv[0]); }
        else if (t == 1) { k = dot16(xr, wk[1]); v = dot16(xr, wv[1]); }
        else             { k = dot16(xr, wk[2]); v = dot16(xr, wv[2]); }
        const int pk = __builtin_amdgcn_cvt_pk_fp8_f32(4.f * k, 4.f * v, 0, false);
        KV[(size_t)n * DD + tid] = (ushort)(pk & 0xffff);
    }
}

// ---- Qt8[n][et][f] fp8 (scale 256 prefolded via Wc); grid (782,3): et pairs {0,1},{2,3},{4}
__global__ __launch_bounds__(128) void qt_kernel(
    const float* __restrict__ x, const int* __restrict__ ntype,
    const float* __restrict__ Wc, unsigned char* __restrict__ Qt8)
{
    const int tid = threadIdx.x;
    const int h = tid >> 4, dd = tid & 15;
    const int et0 = blockIdx.y * 2;
    const int ne = (et0 == 4) ? 1 : 2;
    float w[2][N_NT][HDIM];
#pragma unroll
    for (int e = 0; e < 2; e++) {
        const int et = (et0 + e > 4) ? 4 : et0 + e;
#pragma unroll
        for (int t = 0; t < N_NT; t++)
#pragma unroll
            for (int c = 0; c < HDIM; c++)
                w[e][t][c] = Wc[((((et * N_NT + t) * HH + h) * HDIM + c) * HDIM) + dd];
    }

    __shared__ float xs[DD];
    const int base = blockIdx.x * 64;
    for (int nn = 0; nn < 64; nn++) {
        const int n = base + nn;
        __syncthreads();
        if (n < N_NODESC) xs[tid] = x[(size_t)n * DD + tid];
        __syncthreads();
        if (n >= N_NODESC) continue;
        const int t = ntype[n];
        float xr[HDIM];
#pragma unroll
        for (int c = 0; c < HDIM; c++) xr[c] = xs[h * HDIM + c];
#pragma unroll
        for (int e = 0; e < 2; e++) {
            if (e >= ne) break;
            float q;
            if (t == 0)      q = dot16(xr, w[e][0]);
            else if (t == 1) q = dot16(xr, w[e][1]);
            else             q = dot16(xr, w[e][2]);
            Qt8[((size_t)n * N_ET + et0 + e) * DD + tid] =
                (unsigned char)(__builtin_amdgcn_cvt_pk_fp8_f32(q, q, 0, false) & 0xff);
        }
    }
}

// ---------------- CSR build ----------------
__global__ void deg_kernel(const int* __restrict__ dst, int* __restrict__ deg) {
    const int e = blockIdx.x * 256 + threadIdx.x;
    if (e < N_EDGESC) atomicAdd(&deg[dst[e]], 1);
}

__global__ __launch_bounds__(1024) void scan_kernel(
    const int* __restrict__ deg, int* __restrict__ rowstart)
{
    __shared__ int part[1024];
    const int tid = threadIdx.x;
    const int per = 49;
    const int base = tid * per;
    int s = 0;
    for (int i = 0; i < per; i++) { int idx = base + i; if (idx < N_NODESC) s += deg[idx]; }
    part[tid] = s;
    __syncthreads();
    for (int off = 1; off < 1024; off <<= 1) {
        int v = (tid >= off) ? part[tid - off] : 0;
        __syncthreads();
        part[tid] += v;
        __syncthreads();
    }
    int run = (tid == 0) ? 0 : part[tid - 1];
    for (int i = 0; i < per; i++) {
        int idx = base + i;
        if (idx < N_NODESC) { rowstart[idx] = run; run += deg[idx]; }
    }
    if (tid == 1023) rowstart[N_NODESC] = part[1023];
}

// pack src|et<<16 directly into CSR slot: edgeagg then needs ONE sequential load/edge
__global__ void fill_kernel(const int* __restrict__ src, const int* __restrict__ dst,
                            const int* __restrict__ etype, const int* __restrict__ rowstart,
                            int* __restrict__ cursor, int* __restrict__ edata) {
    const int e = blockIdx.x * 256 + threadIdx.x;
    if (e < N_EDGESC) {
        const int d = dst[e];
        const int p = atomicAdd(&cursor[d], 1);
        edata[rowstart[d] + p] = src[e] | (etype[e] << 16);
    }
}

// ---------------- fused edge pass (fp8 gathers) ----------------
#define PROC(ed, kv) { \
    const int et_ = (ed) >> 16; \
    const float k_ = __builtin_amdgcn_cvt_f32_fp8((int)(kv), 0); \
    const float v_ = __builtin_amdgcn_cvt_f32_fp8((int)(kv), 1); \
    const float qv_ = (et_ == 0) ? q0 : (et_ == 1) ? q1 : (et_ == 2) ? q2 : (et_ == 3) ? q3 : q4; \
    float p_ = qv_ * k_; \
    p_ += __shfl_xor(p_, 1); p_ += __shfl_xor(p_, 2); \
    p_ += __shfl_xor(p_, 4); p_ += __shfl_xor(p_, 8); \
    const float ex_ = __expf(p_ * (1.0f / 1024.0f)); \
    den += ex_; acc = fmaf(ex_, v_, acc); }

__global__ __launch_bounds__(128) void edgeagg_kernel(
    const int* __restrict__ rowstart, const int* __restrict__ edata,
    const unsigned char* __restrict__ Qt8, const ushort* __restrict__ KV,
    ushort* __restrict__ agg)
{
    const int n = blockIdx.x;
    const int f = threadIdx.x;
    const float q0 = __builtin_amdgcn_cvt_f32_fp8((int)Qt8[((size_t)n * N_ET + 0) * DD + f], 0);
    const float q1 = __builtin_amdgcn_cvt_f32_fp8((int)Qt8[((size_t)n * N_ET + 1) * DD + f], 0);
    const float q2 = __builtin_amdgcn_cvt_f32_fp8((int)Qt8[((size_t)n * N_ET + 2) * DD + f], 0);
    const float q3 = __builtin_amdgcn_cvt_f32_fp8((int)Qt8[((size_t)n * N_ET + 3) * DD + f], 0);
    const float q4 = __builtin_amdgcn_cvt_f32_fp8((int)Qt8[((size_t)n * N_ET + 4) * DD + f], 0);

    const int s0 = rowstart[n], s1 = rowstart[n + 1];
    float acc = 0.f, den = 0.f;
    int i = s0;
    for (; i + 3 < s1; i += 4) {
        const int e0 = edata[i], e1 = edata[i + 1], e2 = edata[i + 2], e3 = edata[i + 3];
        const ushort kv0 = KV[(size_t)(e0 & 0xffff) * DD + f];
        const ushort kv1 = KV[(size_t)(e1 & 0xffff) * DD + f];
        const ushort kv2 = KV[(size_t)(e2 & 0xffff) * DD + f];
        const ushort kv3 = KV[(size_t)(e3 & 0xffff) * DD + f];
        PROC(e0, kv0); PROC(e1, kv1); PROC(e2, kv2); PROC(e3, kv3);
    }
    for (; i < s1; i++) {
        const int e0 = edata[i];
        const ushort kv0 = KV[(size_t)(e0 & 0xffff) * DD + f];
        PROC(e0, kv0);
    }
    // undo V scale (x4): 0.25
    agg[(size_t)n * DD + f] = f2b(0.25f * acc / (den + 1e-10f));
}

// ---- weight transposes to bf16 [N][K] for MFMA B-operand ----
__global__ __launch_bounds__(256) void convert_wt(
    const float* __restrict__ Wout, const float* __restrict__ W1, const float* __restrict__ W2,
    ushort* __restrict__ Woutt, ushort* __restrict__ W1t, ushort* __restrict__ W2t)
{
    const int gid = blockIdx.x * 256 + threadIdx.x;
    if (gid < 16384) {
        const int nn = gid >> 7, k = gid & 127;
        Woutt[gid] = f2b(Wout[k * 128 + nn]);
    } else if (gid < 16384 + 65536) {
        const int i = gid - 16384;
        const int nn = i >> 7, k = i & 127;
        W1t[i] = f2b(W1[k * 512 + nn]);
    } else if (gid < 16384 + 131072) {
        const int i = gid - 81920;
        const int nn = i >> 9, k = i & 511;
        W2t[i] = f2b(W2[k * 128 + nn]);
    }
}

// ---------------- MFMA bf16 GEMM 128x128 tile, BK=32, fused epilogues ----------------
// EPI 0: T = bf16 gelu(acc + bias)        (ffn1, grid.y = N/128)
// EPI 1: h1b = bf16 LN(acc + bias + residF)   (attn out, N=128)
// EPI 2: out = f32 LN(acc + bias + b2f(residB)) (ffn2, N=128)
#define LDP 40

template<int KT, int EPI>
__global__ __launch_bounds__(256) void mfma_gemm(
    const ushort* __restrict__ A, const ushort* __restrict__ Bt,
    const float* __restrict__ bias,
    const float* __restrict__ residF, const ushort* __restrict__ residB,
    const float* __restrict__ g, const float* __restrict__ b,
    float* __restrict__ outF, ushort* __restrict__ outB, int ldOut)
{
    __shared__ ushort As[128 * LDP];
    __shared__ ushort Bs[128 * LDP];
    __shared__ float red[2][2][128];
    const int tid = threadIdx.x;
    const int lane = tid & 63, wave = tid >> 6;
    const int mw = (wave >> 1) * 64, nw = (wave & 1) * 64;
    const int mBase = blockIdx.x * 128, nBase = blockIdx.y * 128;
    const int l15 = lane & 15, q8 = (lane >> 4) * 8;

    f32x4 acc[4][4];
#pragma unroll
    for (int i = 0; i < 4; i++)
#pragma unroll
        for (int j = 0; j < 4; j++) acc[i][j] = (f32x4){0.f, 0.f, 0.f, 0.f};

    const int r0 = tid >> 2;
    const int c0 = (tid & 3) * 8;

    for (int kk = 0; kk < KT; kk += 32) {
        const ushort* pa = A  + (size_t)(mBase + r0) * KT + kk + c0;
        const ushort* pb = Bt + (size_t)(nBase + r0) * KT + kk + c0;
        short8 a0 = *(const short8*)pa;
        short8 a1 = *(const short8*)(pa + (size_t)64 * KT);
        short8 b0 = *(const short8*)pb;
        short8 b1 = *(const short8*)(pb + (size_t)64 * KT);
        *(short8*)&As[r0 * LDP + c0] = a0;
        *(short8*)&As[(r0 + 64) * LDP + c0] = a1;
        *(short8*)&Bs[r0 * LDP + c0] = b0;
        *(short8*)&Bs[(r0 + 64) * LDP + c0] = b1;
        __syncthreads();

        short8 af[4], bf[4];
#pragma unroll
        for (int i = 0; i < 4; i++)
            af[i] = *(const short8*)&As[(mw + i * 16 + l15) * LDP + q8];
#pragma unroll
        for (int j = 0; j < 4; j++)
            bf[j] = *(const short8*)&Bs[(nw + j * 16 + l15) * LDP + q8];
#pragma unroll
        for (int i = 0; i < 4; i++)
#pragma unroll
            for (int j = 0; j < 4; j++)
                acc[i][j] = __builtin_amdgcn_mfma_f32_16x16x32_bf16(af[i], bf[j], acc[i][j], 0, 0, 0);
        __syncthreads();
    }

    const int rq = (lane >> 4) * 4;

    if (EPI == 0) {
        // gelu -> bf16
#pragma unroll
        for (int i = 0; i < 4; i++) {
#pragma unroll
            for (int r = 0; r < 4; r++) {
                const int gm = mBase + mw + i * 16 + rq + r;
                if (gm >= N_NODESC) continue;
#pragma unroll
                for (int j = 0; j < 4; j++) {
                    const int gn = nBase + nw + j * 16 + l15;
                    float v = acc[i][j][r] + bias[gn];
                    v = 0.5f * v * (1.f + erff(v * 0.70710678118654752f));
                    outB[(size_t)gm * ldOut + gn] = f2b(v);
                }
            }
        }
    } else {
        // LN epilogue over full feature dim (N=128, nBase=0)
        float biasv[4], gv[4], bv[4];
#pragma unroll
        for (int j = 0; j < 4; j++) {
            const int gn = nw + j * 16 + l15;
            biasv[j] = bias[gn]; gv[j] = g[gn]; bv[j] = b[gn];
        }
#pragma unroll
        for (int i = 0; i < 4; i++) {
#pragma unroll
            for (int r = 0; r < 4; r++) {
                const int row = mw + i * 16 + rq + r;
                const int gm = mBase + row;
                float s = 0.f, ss = 0.f;
#pragma unroll
                for (int j = 0; j < 4; j++) {
                    const int gn = nw + j * 16 + l15;
                    float v = acc[i][j][r] + biasv[j];
                    if (EPI == 1) v += (gm < N_NODESC) ? residF[(size_t)gm * DD + gn] : 0.f;
                    else          v += (gm < N_NODESC) ? b2f(residB[(size_t)gm * DD + gn]) : 0.f;
                    acc[i][j][r] = v;
                    s += v; ss += v * v;
                }
                s  += __shfl_xor(s, 1);  s  += __shfl_xor(s, 2);  s  += __shfl_xor(s, 4);  s  += __shfl_xor(s, 8);
                ss += __shfl_xor(ss, 1); ss += __shfl_xor(ss, 2); ss += __shfl_xor(ss, 4); ss += __shfl_xor(ss, 8);
                if (l15 == 0) { red[0][nw >> 6][row] = s; red[1][nw >> 6][row] = ss; }
            }
        }
        __syncthreads();
#pragma unroll
        for (int i = 0; i < 4; i++) {
#pragma unroll
            for (int r = 0; r < 4; r++) {
                const int row = mw + i * 16 + rq + r;
                const int gm = mBase + row;
                if (gm >= N_NODESC) continue;
                const float s  = red[0][0][row] + red[0][1][row];
                const float ss = red[1][0][row] + red[1][1][row];
                const float mean = s * (1.f / 128.f);
                const float var  = ss * (1.f / 128.f) - mean * mean;
                const float rstd = rsqrtf(var + 1e-5f);
#pragma unroll
                for (int j = 0; j < 4; j++) {
                    const int gn = nw + j * 16 + l15;
                    const float o = (acc[i][j][r] - mean) * rstd * gv[j] + bv[j];
                    if (EPI == 1) outB[(size_t)gm * DD + gn] = f2b(o);
                    else          outF[(size_t)gm * DD + gn] = o;
                }
            }
        }
    }
}

extern "C" void kernel_launch(void* const* d_in, const int* in_sizes, int n_in,
                              void* d_out, int out_size, void* d_ws, size_t ws_size,
                              hipStream_t stream)
{
    const float* x     = (const float*)d_in[0];
    const int*   ei    = (const int*)d_in[1];
    const int*   etyp  = (const int*)d_in[2];
    const int*   ntype = (const int*)d_in[3];
    const float* Wq    = (const float*)d_in[4];
    const float* Wk    = (const float*)d_in[5];
    const float* Wv    = (const float*)d_in[6];
    const float* We    = (const float*)d_in[7];
    const float* mu    = (const float*)d_in[8];
    const float* Wout  = (const float*)d_in[9];
    const float* bout  = (const float*)d_in[10];
    const float* g1    = (const float*)d_in[11];
    const float* b1ln  = (const float*)d_in[12];
    const float* W1    = (const float*)d_in[13];
    const float* b1    = (const float*)d_in[14];
    const float* W2    = (const float*)d_in[15];
    const float* b2    = (const float*)d_in[16];
    const float* g2    = (const float*)d_in[17];
    const float* b2ln  = (const float*)d_in[18];
    float* out = (float*)d_out;

    char* ws = (char*)d_ws;
    ushort*        KV    = (ushort*)(ws + KV_OFF);
    unsigned char* Qt8   = (unsigned char*)(ws + QT8_OFF);
    ushort*        T     = (ushort*)(ws + T_OFF);
    ushort*        agg   = (ushort*)(ws + AGG_OFF);
    ushort*        h1b   = (ushort*)(ws + H1B_OFF);
    ushort*        Woutt = (ushort*)(ws + WOUTT_OFF);
    ushort*        W1t   = (ushort*)(ws + W1T_OFF);
    ushort*        W2t   = (ushort*)(ws + W2T_OFF);
    float*         Wc    = (float*)(ws + WC_OFF);
    int*           edata = (int*)(ws + EDATA_OFF);
    int*           rows  = (int*)(ws + ROWS_OFF);
    int*           deg   = (int*)(ws + DEG_OFF);
    int*           cur   = (int*)(ws + CUR_OFF);

    const int* srcA = ei;
    const int* dstA = ei + N_EDGESC;

    hipMemsetAsync(ws + DEG_OFF, 0, 400064, stream);

    convert_wt<<<576, 256, 0, stream>>>(Wout, W1, W2, Woutt, W1t, W2t);
    wc_kernel<<<dim3(N_ET, N_NT, HH), 256, 0, stream>>>(Wq, We, mu, Wc);
    kv_kernel<<<782, 128, 0, stream>>>(x, ntype, Wk, Wv, KV);
    qt_kernel<<<dim3(782, 3), 128, 0, stream>>>(x, ntype, Wc, Qt8);
    deg_kernel<<<3125, 256, 0, stream>>>(dstA, deg);
    scan_kernel<<<1, 1024, 0, stream>>>(deg, rows);
    fill_kernel<<<3125, 256, 0, stream>>>(srcA, dstA, etyp, rows, cur, edata);
    edgeagg_kernel<<<N_NODESC, 128, 0, stream>>>(rows, edata, Qt8, KV, agg);

    // h1b = LN1(agg @ Wout + bout + x)  (bf16)
    mfma_gemm<128, 1><<<391, 256, 0, stream>>>(agg, Woutt, bout, x, nullptr, g1, b1ln, nullptr, h1b, 128);
    // T = gelu(h1b @ W1 + b1)  (bf16)
    mfma_gemm<128, 0><<<dim3(391, 4), 256, 0, stream>>>(h1b, W1t, b1, nullptr, nullptr, nullptr, nullptr, nullptr, T, 512);
    // out = LN2(T @ W2 + b2 + h1b)  (f32)
    mfma_gemm<512, 2><<<391, 256, 0, stream>>>(T, W2t, b2, nullptr, h1b, g2, b2ln, out, nullptr, 128);
}